// Round 3
// baseline (114.036 us; speedup 1.0000x reference)
//
#include <hip/hip_runtime.h>

#define T_DIM 2048
#define F_DIM 512
#define B_DIM 64
#define NC 8                    // T-chunks per sequence
#define CHUNK (T_DIM / NC)      // 256
#define WARM 48                 // cold-start decay: C(51,3)*p^48 ~ 1.1e-3 rel
#define UNROLL 8                // time-steps per register buffer
#define VEC 4                   // features per thread (float4)
#define F4 (F_DIM / VEC)        // 128

// One thread per (batch, 4-feature group, T-chunk). float4 loads/stores:
// 16B/lane, 1KB contiguous per wave transaction (matches the 6.3TB/s copy
// pattern; round-2 evidence says we're transaction-shape-bound, not
// occupancy-bound). Chunks c>0 warm up 48 samples from a cold reset init.

#define IIR_ONE(xn, X1, X2, X3, X4, Y1, Y2, Y3, Y4, OUT)            \
    {                                                               \
        float acc = b0 * (xn);                                      \
        acc = fmaf(b1, X1, acc);                                    \
        acc = fmaf(b2, X2, acc);                                    \
        acc = fmaf(b3, X3, acc);                                    \
        acc = fmaf(b4, X4, acc);                                    \
        acc = fmaf(-a4, Y4, acc);                                   \
        acc = fmaf(-a3, Y3, acc);                                   \
        acc = fmaf(-a2, Y2, acc);                                   \
        const float yn = fmaf(-a1, Y1, acc); /* 1-FMA critical chain */ \
        X4 = X3; X3 = X2; X2 = X1; X1 = (xn);                       \
        Y4 = Y3; Y3 = Y2; Y2 = Y1; Y1 = yn;                         \
        OUT = yn;                                                   \
    }

#define IIR_STEP(SRC, DSTV, I)                                      \
    {                                                               \
        const float4 xnv = SRC[I];                                  \
        float4 ynv;                                                 \
        IIR_ONE(xnv.x, x1_0, x2_0, x3_0, x4_0, y1_0, y2_0, y3_0, y4_0, ynv.x) \
        IIR_ONE(xnv.y, x1_1, x2_1, x3_1, x4_1, y1_1, y2_1, y3_1, y4_1, ynv.y) \
        IIR_ONE(xnv.z, x1_2, x2_2, x3_2, x4_2, y1_2, y2_2, y3_2, y4_2, ynv.z) \
        IIR_ONE(xnv.w, x1_3, x2_3, x3_3, x4_3, y1_3, y2_3, y3_3, y4_3, ynv.w) \
        DSTV[I] = ynv;                                              \
    }

__global__ __launch_bounds__(256) void lowpass_iir_kernel(
    const float* __restrict__ x, const float* __restrict__ bc,
    const float* __restrict__ ac, float* __restrict__ y)
{
    const int tid = blockIdx.x * blockDim.x + threadIdx.x;
    const int f4 = tid & (F4 - 1);
    const int c  = (tid >> 7) & (NC - 1);
    const int b  = tid >> 10;

    const int nwarm  = c ? WARM : 0;              // 0 or 48
    const int start  = c * CHUNK - nwarm;
    const int ntot   = CHUNK + nwarm;             // 256 or 304
    const int nch    = ntot / UNROLL;             // 32 or 38 (both even)
    const int warmch = nwarm / UNROLL;            // 0 or 6

    const size_t base = (size_t)b * (size_t)(T_DIM * F_DIM)
                      + (size_t)start * F_DIM + (size_t)(f4 * VEC);
    const float4* __restrict__ xin  = (const float4*)(x + base);
    float4* __restrict__       yout = (float4*)(y + base);

    // Coefficients (wave-uniform -> scalar loads)
    const float b0 = bc[0], b1 = bc[1], b2 = bc[2], b3 = bc[3], b4 = bc[4];
    const float a1 = ac[1], a2 = ac[2], a3 = ac[3], a4 = ac[4];

    // reset() at `start`: both histories filled with the first sample there
    const float4 x0v = xin[0];
    float x1_0 = x0v.x, x2_0 = x0v.x, x3_0 = x0v.x, x4_0 = x0v.x;
    float y1_0 = x0v.x, y2_0 = x0v.x, y3_0 = x0v.x, y4_0 = x0v.x;
    float x1_1 = x0v.y, x2_1 = x0v.y, x3_1 = x0v.y, x4_1 = x0v.y;
    float y1_1 = x0v.y, y2_1 = x0v.y, y3_1 = x0v.y, y4_1 = x0v.y;
    float x1_2 = x0v.z, x2_2 = x0v.z, x3_2 = x0v.z, x4_2 = x0v.z;
    float y1_2 = x0v.z, y2_2 = x0v.z, y3_2 = x0v.z, y4_2 = x0v.z;
    float x1_3 = x0v.w, x2_3 = x0v.w, x3_3 = x0v.w, x4_3 = x0v.w;
    float y1_3 = x0v.w, y2_3 = x0v.w, y3_3 = x0v.w, y4_3 = x0v.w;

    float4 bufA[UNROLL], bufB[UNROLL], yvA[UNROLL], yvB[UNROLL];

    // Prologue: load chunk 0
    #pragma unroll
    for (int i = 0; i < UNROLL; ++i)
        bufA[i] = xin[(size_t)i * F4];

    #pragma unroll 1
    for (int c0 = 0; c0 < nch; c0 += 2) {
        // Prefetch odd chunk while computing even chunk
        #pragma unroll
        for (int i = 0; i < UNROLL; ++i)
            bufB[i] = xin[(size_t)((c0 + 1) * UNROLL + i) * F4];

        #pragma unroll
        for (int i = 0; i < UNROLL; ++i)
            IIR_STEP(bufA, yvA, i)
        if (c0 >= warmch) {
            #pragma unroll
            for (int i = 0; i < UNROLL; ++i)
                yout[(size_t)(c0 * UNROLL + i) * F4] = yvA[i];
        }

        // Prefetch next even chunk while computing odd chunk
        if (c0 + 2 < nch) {
            #pragma unroll
            for (int i = 0; i < UNROLL; ++i)
                bufA[i] = xin[(size_t)((c0 + 2) * UNROLL + i) * F4];
        }

        #pragma unroll
        for (int i = 0; i < UNROLL; ++i)
            IIR_STEP(bufB, yvB, i)
        if (c0 + 1 >= warmch) {
            #pragma unroll
            for (int i = 0; i < UNROLL; ++i)
                yout[(size_t)((c0 + 1) * UNROLL + i) * F4] = yvB[i];
        }
    }
}

extern "C" void kernel_launch(void* const* d_in, const int* in_sizes, int n_in,
                              void* d_out, int out_size, void* d_ws, size_t ws_size,
                              hipStream_t stream) {
    const float* x = (const float*)d_in[0];
    const float* b = (const float*)d_in[1];
    const float* a = (const float*)d_in[2];
    float* y = (float*)d_out;

    const int total_threads = B_DIM * F4 * NC;   // 64*128*8 = 65536
    const int block = 256;
    const int grid = total_threads / block;      // 256 blocks -> 1 per CU
    lowpass_iir_kernel<<<grid, block, 0, stream>>>(x, b, a, y);
}

// Round 4
// 88.830 us; speedup vs baseline: 1.2838x; 1.2838x over previous
//
#include <hip/hip_runtime.h>

#define T_DIM 2048
#define F_DIM 512
#define B_DIM 64
#define NC 8                    // T-chunks per sequence
#define CHUNK (T_DIM / NC)      // 256
#define WARM 48                 // cold-start decay: C(51,3)*p^48 ~ 1.1e-3 rel
#define UNROLL 8                // time-steps per register buffer
#define VEC 2                   // features per thread (float2)
#define F2 (F_DIM / VEC)        // 256

typedef float f32x2 __attribute__((ext_vector_type(2)));

// One thread per (batch, 2-feature group, T-chunk); a 256-thread block covers
// one full 2KB row of one (b,c) stream -> minimal co-advancing DRAM streams.
// y stores are NONTEMPORAL (no L2/L3 allocate): y is write-once dead data and
// its allocations were churning the 256MiB L3 that x (exactly 256MiB) could
// otherwise live in across graph replays. x loads stay temporal.

#define IIR_ONE(xn, X1, X2, X3, X4, Y1, Y2, Y3, Y4, OUT)            \
    {                                                               \
        float acc = b0 * (xn);                                      \
        acc = fmaf(b1, X1, acc);                                    \
        acc = fmaf(b2, X2, acc);                                    \
        acc = fmaf(b3, X3, acc);                                    \
        acc = fmaf(b4, X4, acc);                                    \
        acc = fmaf(-a4, Y4, acc);                                   \
        acc = fmaf(-a3, Y3, acc);                                   \
        acc = fmaf(-a2, Y2, acc);                                   \
        const float yn = fmaf(-a1, Y1, acc); /* 1-FMA critical chain */ \
        X4 = X3; X3 = X2; X2 = X1; X1 = (xn);                       \
        Y4 = Y3; Y3 = Y2; Y2 = Y1; Y1 = yn;                         \
        OUT = yn;                                                   \
    }

#define IIR_STEP(SRC, DSTV, I)                                      \
    {                                                               \
        const f32x2 xnv = SRC[I];                                   \
        f32x2 ynv;                                                  \
        IIR_ONE(xnv.x, x1_0, x2_0, x3_0, x4_0, y1_0, y2_0, y3_0, y4_0, ynv.x) \
        IIR_ONE(xnv.y, x1_1, x2_1, x3_1, x4_1, y1_1, y2_1, y3_1, y4_1, ynv.y) \
        DSTV[I] = ynv;                                              \
    }

__global__ __launch_bounds__(256) void lowpass_iir_kernel(
    const float* __restrict__ x, const float* __restrict__ bc,
    const float* __restrict__ ac, float* __restrict__ y)
{
    const int tid = blockIdx.x * blockDim.x + threadIdx.x;
    const int f2 = tid & (F2 - 1);
    const int c  = (tid >> 8) & (NC - 1);
    const int b  = tid >> 11;

    const int nwarm  = c ? WARM : 0;              // 0 or 48
    const int start  = c * CHUNK - nwarm;
    const int ntot   = CHUNK + nwarm;             // 256 or 304
    const int nch    = ntot / UNROLL;             // 32 or 38 (both even)
    const int warmch = nwarm / UNROLL;            // 0 or 6

    const size_t base = (size_t)b * (size_t)(T_DIM * F_DIM)
                      + (size_t)start * F_DIM + (size_t)(f2 * VEC);
    const f32x2* __restrict__ xin  = (const f32x2*)(x + base);
    f32x2* __restrict__       yout = (f32x2*)(y + base);

    // Coefficients (wave-uniform -> scalar loads)
    const float b0 = bc[0], b1 = bc[1], b2 = bc[2], b3 = bc[3], b4 = bc[4];
    const float a1 = ac[1], a2 = ac[2], a3 = ac[3], a4 = ac[4];

    // reset() at `start`: both histories filled with the first sample there
    const f32x2 x0v = xin[0];
    float x1_0 = x0v.x, x2_0 = x0v.x, x3_0 = x0v.x, x4_0 = x0v.x;
    float y1_0 = x0v.x, y2_0 = x0v.x, y3_0 = x0v.x, y4_0 = x0v.x;
    float x1_1 = x0v.y, x2_1 = x0v.y, x3_1 = x0v.y, x4_1 = x0v.y;
    float y1_1 = x0v.y, y2_1 = x0v.y, y3_1 = x0v.y, y4_1 = x0v.y;

    f32x2 bufA[UNROLL], bufB[UNROLL], yvA[UNROLL], yvB[UNROLL];

    // Prologue: load chunk 0
    #pragma unroll
    for (int i = 0; i < UNROLL; ++i)
        bufA[i] = xin[(size_t)i * F2];

    #pragma unroll 1
    for (int c0 = 0; c0 < nch; c0 += 2) {
        // Prefetch odd chunk while computing even chunk
        #pragma unroll
        for (int i = 0; i < UNROLL; ++i)
            bufB[i] = xin[(size_t)((c0 + 1) * UNROLL + i) * F2];

        #pragma unroll
        for (int i = 0; i < UNROLL; ++i)
            IIR_STEP(bufA, yvA, i)
        if (c0 >= warmch) {
            #pragma unroll
            for (int i = 0; i < UNROLL; ++i)
                __builtin_nontemporal_store(yvA[i],
                    &yout[(size_t)(c0 * UNROLL + i) * F2]);
        }

        // Prefetch next even chunk while computing odd chunk
        if (c0 + 2 < nch) {
            #pragma unroll
            for (int i = 0; i < UNROLL; ++i)
                bufA[i] = xin[(size_t)((c0 + 2) * UNROLL + i) * F2];
        }

        #pragma unroll
        for (int i = 0; i < UNROLL; ++i)
            IIR_STEP(bufB, yvB, i)
        if (c0 + 1 >= warmch) {
            #pragma unroll
            for (int i = 0; i < UNROLL; ++i)
                __builtin_nontemporal_store(yvB[i],
                    &yout[(size_t)((c0 + 1) * UNROLL + i) * F2]);
        }
    }
}

extern "C" void kernel_launch(void* const* d_in, const int* in_sizes, int n_in,
                              void* d_out, int out_size, void* d_ws, size_t ws_size,
                              hipStream_t stream) {
    const float* x = (const float*)d_in[0];
    const float* b = (const float*)d_in[1];
    const float* a = (const float*)d_in[2];
    float* y = (float*)d_out;

    const int total_threads = B_DIM * F2 * NC;   // 64*256*8 = 131072
    const int block = 256;
    const int grid = total_threads / block;      // 512 blocks -> 8 waves/CU
    lowpass_iir_kernel<<<grid, block, 0, stream>>>(x, b, a, y);
}

// Round 5
// 83.706 us; speedup vs baseline: 1.3623x; 1.0612x over previous
//
#include <hip/hip_runtime.h>

#define T_DIM 2048
#define F_DIM 512
#define B_DIM 64
#define NC 4                    // T-chunks per sequence
#define CHUNK (T_DIM / NC)      // 512
#define WARM 48                 // cold-start decay: C(51,3)*p^48 ~ 1.1e-3 rel
#define UNROLL 8                // time-steps per register buffer
#define VEC 2                   // features per thread (float2)
#define F2 (F_DIM / VEC)        // 256

typedef float f32x2 __attribute__((ext_vector_type(2)));

// One thread per (batch, 2-feature group, T-chunk); a 256-thread block covers
// one full 2KB row of one (b,c) stream. y stores are NONTEMPORAL (no L3
// allocate): round-4 evidence shows x (exactly 256MiB = L3 size) then gets
// ~48% L3 hits across graph replays (FETCH 300->156MB). NC=8->4 trims the
// warm-up re-read demand 44->19MB to push the read footprint closer to L3
// capacity (capacity-edge thrashing is superlinear in excess footprint).
// Grid = 256 blocks = 1/CU, 4 waves/CU (round 2: occupancy beyond this is
// not the binding constraint).

#define IIR_ONE(xn, X1, X2, X3, X4, Y1, Y2, Y3, Y4, OUT)            \
    {                                                               \
        float acc = b0 * (xn);                                      \
        acc = fmaf(b1, X1, acc);                                    \
        acc = fmaf(b2, X2, acc);                                    \
        acc = fmaf(b3, X3, acc);                                    \
        acc = fmaf(b4, X4, acc);                                    \
        acc = fmaf(-a4, Y4, acc);                                   \
        acc = fmaf(-a3, Y3, acc);                                   \
        acc = fmaf(-a2, Y2, acc);                                   \
        const float yn = fmaf(-a1, Y1, acc); /* 1-FMA critical chain */ \
        X4 = X3; X3 = X2; X2 = X1; X1 = (xn);                       \
        Y4 = Y3; Y3 = Y2; Y2 = Y1; Y1 = yn;                         \
        OUT = yn;                                                   \
    }

#define IIR_STEP(SRC, DSTV, I)                                      \
    {                                                               \
        const f32x2 xnv = SRC[I];                                   \
        f32x2 ynv;                                                  \
        IIR_ONE(xnv.x, x1_0, x2_0, x3_0, x4_0, y1_0, y2_0, y3_0, y4_0, ynv.x) \
        IIR_ONE(xnv.y, x1_1, x2_1, x3_1, x4_1, y1_1, y2_1, y3_1, y4_1, ynv.y) \
        DSTV[I] = ynv;                                              \
    }

__global__ __launch_bounds__(256) void lowpass_iir_kernel(
    const float* __restrict__ x, const float* __restrict__ bc,
    const float* __restrict__ ac, float* __restrict__ y)
{
    const int tid = blockIdx.x * blockDim.x + threadIdx.x;
    const int f2 = tid & (F2 - 1);
    const int c  = (tid >> 8) & (NC - 1);
    const int b  = tid >> 10;

    const int nwarm  = c ? WARM : 0;              // 0 or 48
    const int start  = c * CHUNK - nwarm;
    const int ntot   = CHUNK + nwarm;             // 512 or 560
    const int nch    = ntot / UNROLL;             // 64 or 70 (both even)
    const int warmch = nwarm / UNROLL;            // 0 or 6

    const size_t base = (size_t)b * (size_t)(T_DIM * F_DIM)
                      + (size_t)start * F_DIM + (size_t)(f2 * VEC);
    const f32x2* __restrict__ xin  = (const f32x2*)(x + base);
    f32x2* __restrict__       yout = (f32x2*)(y + base);

    // Coefficients (wave-uniform -> scalar loads)
    const float b0 = bc[0], b1 = bc[1], b2 = bc[2], b3 = bc[3], b4 = bc[4];
    const float a1 = ac[1], a2 = ac[2], a3 = ac[3], a4 = ac[4];

    // reset() at `start`: both histories filled with the first sample there
    const f32x2 x0v = xin[0];
    float x1_0 = x0v.x, x2_0 = x0v.x, x3_0 = x0v.x, x4_0 = x0v.x;
    float y1_0 = x0v.x, y2_0 = x0v.x, y3_0 = x0v.x, y4_0 = x0v.x;
    float x1_1 = x0v.y, x2_1 = x0v.y, x3_1 = x0v.y, x4_1 = x0v.y;
    float y1_1 = x0v.y, y2_1 = x0v.y, y3_1 = x0v.y, y4_1 = x0v.y;

    f32x2 bufA[UNROLL], bufB[UNROLL], yvA[UNROLL], yvB[UNROLL];

    // Prologue: load chunk 0
    #pragma unroll
    for (int i = 0; i < UNROLL; ++i)
        bufA[i] = xin[(size_t)i * F2];

    #pragma unroll 1
    for (int c0 = 0; c0 < nch; c0 += 2) {
        // Prefetch odd chunk while computing even chunk
        #pragma unroll
        for (int i = 0; i < UNROLL; ++i)
            bufB[i] = xin[(size_t)((c0 + 1) * UNROLL + i) * F2];

        #pragma unroll
        for (int i = 0; i < UNROLL; ++i)
            IIR_STEP(bufA, yvA, i)
        if (c0 >= warmch) {
            #pragma unroll
            for (int i = 0; i < UNROLL; ++i)
                __builtin_nontemporal_store(yvA[i],
                    &yout[(size_t)(c0 * UNROLL + i) * F2]);
        }

        // Prefetch next even chunk while computing odd chunk
        if (c0 + 2 < nch) {
            #pragma unroll
            for (int i = 0; i < UNROLL; ++i)
                bufA[i] = xin[(size_t)((c0 + 2) * UNROLL + i) * F2];
        }

        #pragma unroll
        for (int i = 0; i < UNROLL; ++i)
            IIR_STEP(bufB, yvB, i)
        if (c0 + 1 >= warmch) {
            #pragma unroll
            for (int i = 0; i < UNROLL; ++i)
                __builtin_nontemporal_store(yvB[i],
                    &yout[(size_t)((c0 + 1) * UNROLL + i) * F2]);
        }
    }
}

extern "C" void kernel_launch(void* const* d_in, const int* in_sizes, int n_in,
                              void* d_out, int out_size, void* d_ws, size_t ws_size,
                              hipStream_t stream) {
    const float* x = (const float*)d_in[0];
    const float* b = (const float*)d_in[1];
    const float* a = (const float*)d_in[2];
    float* y = (float*)d_out;

    const int total_threads = B_DIM * F2 * NC;   // 64*256*4 = 65536
    const int block = 256;
    const int grid = total_threads / block;      // 256 blocks -> 1 per CU
    lowpass_iir_kernel<<<grid, block, 0, stream>>>(x, b, a, y);
}